// Round 7
// baseline (397.695 us; speedup 1.0000x reference)
//
#include <hip/hip_runtime.h>
#include <hip/hip_cooperative_groups.h>

namespace cg = cooperative_groups;

#define DIM 64
#define GPW 4    // 16-row groups per wave in gemm
#define BSHIFT 9
#define BSPAN 512      // nodes per bucket
#define MAXNB 512      // max buckets (N <= 262144; here N=200000 -> NB=391)

typedef __attribute__((ext_vector_type(8))) __bf16 bf16x8;
typedef __attribute__((ext_vector_type(4))) __bf16 bf16x4;
typedef __attribute__((ext_vector_type(8))) unsigned short u16x8;
typedef __attribute__((ext_vector_type(4))) float f32x4;

__device__ __forceinline__ f32x4 mfma16(bf16x8 a, bf16x8 b, f32x4 c) {
    return __builtin_amdgcn_mfma_f32_16x16x32_bf16(a, b, c, 0, 0, 0);
}

__device__ __forceinline__ float bf2f(unsigned short u) {
    return __uint_as_float((unsigned)u << 16);
}

// ---------- cooperative CSR build (replaces 5 kernels with 1) ----------
// Phases: zero -> sync -> bucket histogram -> sync -> per-block redundant
// scan of bcnt (each block gets bptr in LDS; no broadcast kernel) +
// coarse scatter (span reservation bptr + atomicAdd(bcur0)) -> sync ->
// per-bucket fine sort (one bucket per block; grid == NB).
__global__ __launch_bounds__(512) void csr_build_kernel(
    const int* __restrict__ ei, unsigned* __restrict__ packed,
    int* __restrict__ bcnt, int* __restrict__ bcur0,
    int* __restrict__ rowptr, int* __restrict__ srcs,
    float* __restrict__ dinv, int E_, int N_, int NB) {
    cg::grid_group grid = cg::this_grid();
    __shared__ int hist[MAXNB];   // holds bptr (exclusive prefix) after phase 2
    __shared__ int sm[512];       // scratch: chunk-hist, scan, node cursors
    int tid = threadIdx.x;
    int bid = blockIdx.x;
    int nblk = gridDim.x;

    // ---- phase 0: zero global counters ----
    if (bid == 0) {
        bcnt[tid] = 0;
        bcur0[tid] = 0;
        if (tid == 0) rowptr[N_] = E_;
    }
    grid.sync();

    // ---- phase 1: bucket histogram (LDS -> global atomics) ----
    for (int i = tid; i < NB; i += 512) hist[i] = 0;
    __syncthreads();
    int chunk = (E_ + nblk - 1) / nblk;
    int e0 = bid * chunk, e1 = min(E_, e0 + chunk);
    for (int e = e0 + tid; e < e1; e += 512)
        atomicAdd(&hist[ei[E_ + e] >> BSHIFT], 1);
    __syncthreads();
    for (int i = tid; i < NB; i += 512)
        if (hist[i]) atomicAdd(&bcnt[i], hist[i]);
    grid.sync();

    // ---- phase 2: redundant per-block exclusive scan of bcnt -> hist ----
    {
        int v = (tid < NB) ? bcnt[tid] : 0;
        sm[tid] = v;
        __syncthreads();
        for (int off = 1; off < 512; off <<= 1) {
            int t = 0;
            if (tid >= off) t = sm[tid - off];
            __syncthreads();
            if (tid >= off) sm[tid] += t;
            __syncthreads();
        }
        hist[tid] = sm[tid] - v;   // exclusive prefix == bptr[tid]
    }
    __syncthreads();

    // ---- phase 3: coarse scatter into bucket spans ----
    for (int i = tid; i < NB; i += 512) sm[i] = 0;
    __syncthreads();
    for (int e = e0 + tid; e < e1; e += 512)
        atomicAdd(&sm[ei[E_ + e] >> BSHIFT], 1);
    __syncthreads();
    for (int i = tid; i < NB; i += 512) {
        int c = sm[i];
        sm[i] = c ? (hist[i] + atomicAdd(&bcur0[i], c)) : 0;
    }
    __syncthreads();
    for (int e = e0 + tid; e < e1; e += 512) {
        int s = ei[e], d = ei[E_ + e];
        int b = d >> BSHIFT;
        int pos = atomicAdd(&sm[b], 1);
        packed[pos] = ((unsigned)s << BSHIFT) | (unsigned)(d & (BSPAN - 1));
    }
    grid.sync();

    // ---- phase 4: per-bucket fine sort (one bucket per block) ----
    for (int b = bid; b < NB; b += nblk) {
        int beg = hist[b];
        int end2 = (b + 1 < MAXNB) ? hist[b + 1] : E_;
        if (b + 1 == NB) end2 = E_;   // hist[NB] == E_ when NB<512, but be safe
        int node0 = b << BSHIFT;
        int nn = min(BSPAN, N_ - node0);
        sm[tid] = 0;
        __syncthreads();
        for (int i = beg + tid; i < end2; i += 512)
            atomicAdd(&sm[packed[i] & (BSPAN - 1)], 1);
        __syncthreads();
        int deg = sm[tid];
        if (tid < nn) dinv[node0 + tid] = rsqrtf((float)(1 + deg));
        // in-place inclusive scan of sm
        for (int off = 1; off < 512; off <<= 1) {
            int t = 0;
            if (tid >= off) t = sm[tid - off];
            __syncthreads();
            if (tid >= off) sm[tid] += t;
            __syncthreads();
        }
        int ex = sm[tid] - deg;
        if (tid < nn) rowptr[node0 + tid] = beg + ex;
        __syncthreads();
        sm[tid] = ex;                 // node-local cursor
        __syncthreads();
        for (int i = beg + tid; i < end2; i += 512) {
            unsigned p = packed[i];
            int pos = atomicAdd(&sm[p & (BSPAN - 1)], 1);
            srcs[beg + pos] = (int)(p >> BSHIFT);
        }
        __syncthreads();              // before next bucket reuses sm
    }
}

// ---------- layer kernels (R4-verified) ----------

// h'(bf16) = (x @ W) * dinv[row].   MFMA 16x16x32 bf16.
// fp32 path uses NT loads (single-use 51 MB embedding read).
template <bool BF16IN>
__global__ __launch_bounds__(256) void gemm_kernel(
    const void* __restrict__ xa_, const void* __restrict__ xb_, int split,
    const float* __restrict__ W, const float* __restrict__ dinv,
    __bf16* __restrict__ h, int n, int ngroups) {
    int lane = threadIdx.x & 63;
    int q = lane >> 4, t = lane & 15;
    int wv = __builtin_amdgcn_readfirstlane(threadIdx.x >> 6);
    int g0 = (blockIdx.x * 4 + wv) * GPW;
    if (g0 >= ngroups) return;

    bf16x8 Bf[4][2];
#pragma unroll
    for (int nt = 0; nt < 4; ++nt)
#pragma unroll
        for (int kt = 0; kt < 2; ++kt) {
            bf16x8 f;
#pragma unroll
            for (int j = 0; j < 8; ++j)
                f[j] = (__bf16)W[(kt * 32 + q * 8 + j) * DIM + nt * 16 + t];
            Bf[nt][kt] = f;
        }

    auto loadA = [&](int r0, f32x4* raw) {
        int row = r0 + t;
        if (row >= n) row = n - 1;
        if constexpr (BF16IN) {
            const __bf16* xr = (const __bf16*)xa_ + (size_t)row * DIM;
            raw[0] = *(const f32x4*)(xr + q * 8);
            raw[1] = *(const f32x4*)(xr + 32 + q * 8);
        } else {
            const float* xr = (row < split)
                ? ((const float*)xa_ + (size_t)row * DIM)
                : ((const float*)xb_ + (size_t)(row - split) * DIM);
            raw[0] = __builtin_nontemporal_load((const f32x4*)(xr + q * 8));
            raw[1] = __builtin_nontemporal_load((const f32x4*)(xr + q * 8 + 4));
            raw[2] = __builtin_nontemporal_load((const f32x4*)(xr + 32 + q * 8));
            raw[3] = __builtin_nontemporal_load((const f32x4*)(xr + 32 + q * 8 + 4));
        }
    };

    f32x4 cur[4];
    loadA(g0 * 16, cur);

#pragma unroll 1
    for (int gi = 0; gi < GPW; ++gi) {
        int g = g0 + gi;
        if (g >= ngroups) break;
        int r0 = g * 16;
        f32x4 nxt[4];
        bool pf = (gi + 1 < GPW) && (g + 1 < ngroups);
        if (pf) loadA(r0 + 16, nxt);

        bf16x8 A0, A1;
        if constexpr (BF16IN) {
            A0 = __builtin_bit_cast(bf16x8, cur[0]);
            A1 = __builtin_bit_cast(bf16x8, cur[1]);
        } else {
#pragma unroll
            for (int j = 0; j < 4; ++j) {
                A0[j] = (__bf16)cur[0][j]; A0[j + 4] = (__bf16)cur[1][j];
                A1[j] = (__bf16)cur[2][j]; A1[j + 4] = (__bf16)cur[3][j];
            }
        }

        f32x4 z = {0.f, 0.f, 0.f, 0.f};
        f32x4 acc[4];
#pragma unroll
        for (int nt = 0; nt < 4; ++nt)
            acc[nt] = mfma16(A1, Bf[nt][1], mfma16(A0, Bf[nt][0], z));

        f32x4 d4 = *(const f32x4*)(dinv + r0 + q * 4);
#pragma unroll
        for (int nt = 0; nt < 4; ++nt)
#pragma unroll
            for (int reg = 0; reg < 4; ++reg) {
                int row = r0 + q * 4 + reg;
                if (row < n)
                    h[(size_t)row * DIM + nt * 16 + t] =
                        (__bf16)(acc[nt][reg] * d4[reg]);
            }
#pragma unroll
        for (int i = 0; i < 4; ++i) cur[i] = nxt[i];
    }
}

// out[node] = b + dinv[node] * (h'[node] + sum_s h'[s])
// 8 nodes/wave (R4-verified): each 8-lane group owns one node's full row.
// fp32 output uses NT stores (single-use 50 MB; keep h2 L2-resident).
template <typename OutT>
__global__ __launch_bounds__(256) void agg_kernel(
    const int* __restrict__ rowptr, const int* __restrict__ srcs,
    const __bf16* __restrict__ h, const float* __restrict__ bias,
    const float* __restrict__ dinv, OutT* __restrict__ out, int n) {
    int lane = threadIdx.x & 63;
    int t8 = lane & 7;
    int wv = threadIdx.x >> 6;
    int node = (blockIdx.x * 4 + wv) * 8 + (lane >> 3);
    bool alive = node < n;
    int nd = alive ? node : (n - 1);
    int beg = rowptr[nd], end = rowptr[nd + 1];

    u16x8 sv = *(const u16x8*)(h + (size_t)nd * DIM + t8 * 8);
    float acc[8];
#pragma unroll
    for (int j = 0; j < 8; ++j) acc[j] = bf2f(sv[j]);

    int i = beg;
    while (i < end) {
        int idx = i + t8;
        int sl = (idx < end) ? srcs[idx] : 0;
        u16x8 vv[8];
#pragma unroll
        for (int k = 0; k < 8; ++k) {
            int s = __shfl(sl, (lane & 56) | k);
            vv[k] = *(const u16x8*)(h + (size_t)s * DIM + t8 * 8);
        }
#pragma unroll
        for (int k = 0; k < 8; ++k)
            if (i + k < end) {
#pragma unroll
                for (int j = 0; j < 8; ++j) acc[j] += bf2f(vv[k][j]);
            }
        i += 8;
    }

    float dn = dinv[nd];
    f32x4 b0 = *(const f32x4*)(bias + t8 * 8);
    f32x4 b1 = *(const f32x4*)(bias + t8 * 8 + 4);
    if (alive) {
        if constexpr (sizeof(OutT) == 4) {
            f32x4 o0, o1;
#pragma unroll
            for (int j = 0; j < 4; ++j) {
                o0[j] = fmaf(dn, acc[j],     b0[j]);
                o1[j] = fmaf(dn, acc[j + 4], b1[j]);
            }
            float* op = (float*)out + (size_t)node * DIM + t8 * 8;
            __builtin_nontemporal_store(o0, (f32x4*)op);
            __builtin_nontemporal_store(o1, (f32x4*)(op + 4));
        } else {
            bf16x8 o;
#pragma unroll
            for (int j = 0; j < 4; ++j) {
                o[j]     = (__bf16)fmaf(dn, acc[j],     b0[j]);
                o[j + 4] = (__bf16)fmaf(dn, acc[j + 4], b1[j]);
            }
            *(bf16x8*)((__bf16*)out + (size_t)node * DIM + t8 * 8) = o;
        }
    }
}

static inline size_t align16(size_t x) { return (x + 15) & ~(size_t)15; }

extern "C" void kernel_launch(void* const* d_in, const int* in_sizes, int n_in,
                              void* d_out, int out_size, void* d_ws, size_t ws_size,
                              hipStream_t stream) {
    const int* ei         = (const int*)d_in[0];
    const float* user_emb = (const float*)d_in[1];
    const float* item_emb = (const float*)d_in[2];
    const float* W1 = (const float*)d_in[3];
    const float* b1 = (const float*)d_in[4];
    const float* W2 = (const float*)d_in[5];
    const float* b2 = (const float*)d_in[6];
    float* out = (float*)d_out;

    const int E_ = in_sizes[0] / 2;
    const int NU = in_sizes[1] / DIM;
    const int NI = in_sizes[2] / DIM;
    const int N_ = NU + NI;
    const int NB = (N_ + BSPAN - 1) >> BSHIFT;   // 391

    // workspace layout (16B-aligned)
    char* p = (char*)d_ws;
    int* srcs   = (int*)p;               p += align16((size_t)E_ * 4);
    __bf16* h   = (__bf16*)p;            p += align16((size_t)N_ * DIM * 2);
    __bf16* t1  = (__bf16*)p;            p += align16((size_t)N_ * DIM * 2);
    float* dinv = (float*)p;             p += align16((size_t)N_ * 4);
    int* rowptr = (int*)p;               p += align16((size_t)(N_ + 1) * 4);
    int* bcnt   = (int*)p;               p += align16((size_t)MAXNB * 4);
    int* bcur0  = (int*)p;               p += align16((size_t)MAXNB * 4);
    // packed edge buffer aliases t1: fully consumed by csr_build before
    // agg1 writes t1.
    unsigned* packed = (unsigned*)t1;

    // cooperative CSR build: 1 launch instead of 5.
    // grid = NB blocks (391) x 512 thr = 8 waves/block -> well under the
    // co-residency cap (4 blocks/CU x 256 CUs = 1024).
    {
        void* args[] = {
            (void*)&ei, (void*)&packed, (void*)&bcnt, (void*)&bcur0,
            (void*)&rowptr, (void*)&srcs, (void*)&dinv,
            (void*)&E_, (void*)&N_, (void*)&NB,
        };
        hipLaunchCooperativeKernel((const void*)csr_build_kernel,
                                   dim3((unsigned)NB), dim3(512), args, 0, stream);
    }

    int NG = (N_ + 15) / 16;                       // 16-row groups
    int gblocks = (NG + 4 * GPW - 1) / (4 * GPW);  // 4 waves/block
    int ablocks = (N_ + 31) / 32;                  // 32 nodes/block (8/wave)

    // layer 1
    gemm_kernel<false><<<gblocks, 256, 0, stream>>>(user_emb, item_emb, NU,
                                                    W1, dinv, h, N_, NG);
    agg_kernel<__bf16><<<ablocks, 256, 0, stream>>>(rowptr, srcs, h, b1, dinv, t1, N_);
    // layer 2
    gemm_kernel<true><<<gblocks, 256, 0, stream>>>(t1, t1, N_,
                                                   W2, dinv, h, N_, NG);
    agg_kernel<float><<<ablocks, 256, 0, stream>>>(rowptr, srcs, h, b2, dinv, out, N_);
}

// Round 8
// 327.974 us; speedup vs baseline: 1.2126x; 1.2126x over previous
//
#include <hip/hip_runtime.h>

#define DIM 64
#define GPW 4    // 16-row groups per wave in gemm
#define BSHIFT 9
#define BSPAN 512      // nodes per bucket
#define MAXNB 512      // max buckets (N <= 262144; here N=200000 -> NB=391)
#define CSRB 512       // blocks in fused count/scan/scatter (co-resident: 8 waves/blk)

typedef __attribute__((ext_vector_type(8))) __bf16 bf16x8;
typedef __attribute__((ext_vector_type(8))) unsigned short u16x8;
typedef __attribute__((ext_vector_type(4))) float f32x4;

__device__ __forceinline__ f32x4 mfma16(bf16x8 a, bf16x8 b, f32x4 c) {
    return __builtin_amdgcn_mfma_f32_16x16x32_bf16(a, b, c, 0, 0, 0);
}

__device__ __forceinline__ float bf2f(unsigned short u) {
    return __uint_as_float((unsigned)u << 16);
}

// ---------- fused CSR count+scan+scatter (1 kernel, 1 hand barrier) ----------
// The only cross-block handoff inside this kernel is bcnt/bcur0, touched
// exclusively via agent-scope atomics on both sides -> a lightweight
// atomic barrier suffices (no normal-store publication, which is what
// makes cg::grid.sync cost ~50us). packed[] (normal stores) is consumed
// by the NEXT kernel -> kernel boundary provides that flush.
// Cooperative launch is used ONLY for the co-residency guarantee.
__global__ __launch_bounds__(512) void csr_count_scatter_kernel(
    const int* __restrict__ ei, unsigned* __restrict__ packed,
    int* __restrict__ bcnt, int* __restrict__ bcur0, int* __restrict__ bar,
    int* __restrict__ bptr, int* __restrict__ rowptr,
    int E_, int N_, int nblk) {
    __shared__ int hist[MAXNB];
    __shared__ int sm[512];
    int tid = threadIdx.x;
    int bid = blockIdx.x;
    int chunk = (E_ + nblk - 1) / nblk;
    int e0 = bid * chunk, e1 = min(E_, e0 + chunk);

    // ---- P1: bucket histogram (LDS -> agent atomics) ----
    hist[tid] = 0;
    __syncthreads();
    for (int e = e0 + tid; e < e1; e += 512)
        atomicAdd(&hist[ei[E_ + e] >> BSHIFT], 1);
    __syncthreads();
    if (hist[tid]) atomicAdd(&bcnt[tid], hist[tid]);

    // ---- device barrier (atomic-only traffic crosses it) ----
    __syncthreads();
    if (tid == 0) {
        __hip_atomic_fetch_add(bar, 1, __ATOMIC_RELEASE,
                               __HIP_MEMORY_SCOPE_AGENT);
        while (__hip_atomic_load(bar, __ATOMIC_ACQUIRE,
                                 __HIP_MEMORY_SCOPE_AGENT) < nblk)
            __builtin_amdgcn_s_sleep(2);
    }
    __syncthreads();

    // ---- P2: redundant per-block exclusive scan of bcnt ----
    int v = __hip_atomic_load(&bcnt[tid], __ATOMIC_RELAXED,
                              __HIP_MEMORY_SCOPE_AGENT);
    sm[tid] = v;
    __syncthreads();
    for (int off = 1; off < 512; off <<= 1) {
        int t = 0;
        if (tid >= off) t = sm[tid - off];
        __syncthreads();
        if (tid >= off) sm[tid] += t;
        __syncthreads();
    }
    int ex = sm[tid] - v;
    __syncthreads();
    hist[tid] = ex;                 // bptr, block-local copy
    if (bid == 0) {
        bptr[tid] = ex;
        if (tid == 0) { bptr[512] = E_; rowptr[N_] = E_; }
    }
    __syncthreads();

    // ---- P3: chunk hist + span reservation + coarse scatter ----
    sm[tid] = 0;
    __syncthreads();
    for (int e = e0 + tid; e < e1; e += 512)
        atomicAdd(&sm[ei[E_ + e] >> BSHIFT], 1);
    __syncthreads();
    int c = sm[tid];
    sm[tid] = c ? (hist[tid] + atomicAdd(&bcur0[tid], c)) : 0;
    __syncthreads();
    for (int e = e0 + tid; e < e1; e += 512) {
        int s = ei[e], d = ei[E_ + e];
        int b = d >> BSHIFT;
        int pos = atomicAdd(&sm[b], 1);
        packed[pos] = ((unsigned)s << BSHIFT) | (unsigned)(d & (BSPAN - 1));
    }
}

// ---------- per-bucket fine sort (R4-verified) ----------
__global__ __launch_bounds__(256) void bucket_sort_kernel(
    const unsigned* __restrict__ packed, const int* __restrict__ bptr,
    int* __restrict__ rowptr, int* __restrict__ srcs,
    float* __restrict__ dinv, int N_) {
    __shared__ int cnt[BSPAN];
    __shared__ int sc[256];
    int tid = threadIdx.x;
    int b = blockIdx.x;
    int beg = bptr[b], end = bptr[b + 1];
    int node0 = b << BSHIFT;
    int nn = min(BSPAN, N_ - node0);
    cnt[tid] = 0; cnt[tid + 256] = 0;
    __syncthreads();
    for (int i = beg + tid; i < end; i += 256)
        atomicAdd(&cnt[packed[i] & (BSPAN - 1)], 1);
    __syncthreads();
    int degA = cnt[tid], degB = cnt[tid + 256];
    int a0 = cnt[2 * tid], a1 = cnt[2 * tid + 1];
    if (tid < nn) dinv[node0 + tid] = rsqrtf((float)(1 + degA));
    if (tid + 256 < nn) dinv[node0 + tid + 256] = rsqrtf((float)(1 + degB));
    int tot = a0 + a1;
    sc[tid] = tot;
    __syncthreads();
    for (int off = 1; off < 256; off <<= 1) {
        int t = 0;
        if (tid >= off) t = sc[tid - off];
        __syncthreads();
        if (tid >= off) sc[tid] += t;
        __syncthreads();
    }
    int ex = sc[tid] - tot;
    cnt[2 * tid] = ex;
    cnt[2 * tid + 1] = ex + a0;
    __syncthreads();
    if (tid < nn) rowptr[node0 + tid] = beg + cnt[tid];
    if (tid + 256 < nn) rowptr[node0 + tid + 256] = beg + cnt[tid + 256];
    __syncthreads();
    for (int i = beg + tid; i < end; i += 256) {
        unsigned p = packed[i];
        int pos = atomicAdd(&cnt[p & (BSPAN - 1)], 1);
        srcs[beg + pos] = (int)(p >> BSHIFT);
    }
}

// ---------- layer kernels (R4-verified) ----------

// h'(bf16) = (x @ W) * dinv[row].   MFMA 16x16x32 bf16.
template <bool BF16IN>
__global__ __launch_bounds__(256) void gemm_kernel(
    const void* __restrict__ xa_, const void* __restrict__ xb_, int split,
    const float* __restrict__ W, const float* __restrict__ dinv,
    __bf16* __restrict__ h, int n, int ngroups) {
    int lane = threadIdx.x & 63;
    int q = lane >> 4, t = lane & 15;
    int wv = __builtin_amdgcn_readfirstlane(threadIdx.x >> 6);
    int g0 = (blockIdx.x * 4 + wv) * GPW;
    if (g0 >= ngroups) return;

    bf16x8 Bf[4][2];
#pragma unroll
    for (int nt = 0; nt < 4; ++nt)
#pragma unroll
        for (int kt = 0; kt < 2; ++kt) {
            bf16x8 f;
#pragma unroll
            for (int j = 0; j < 8; ++j)
                f[j] = (__bf16)W[(kt * 32 + q * 8 + j) * DIM + nt * 16 + t];
            Bf[nt][kt] = f;
        }

    auto loadA = [&](int r0, f32x4* raw) {
        int row = r0 + t;
        if (row >= n) row = n - 1;
        if constexpr (BF16IN) {
            const __bf16* xr = (const __bf16*)xa_ + (size_t)row * DIM;
            raw[0] = *(const f32x4*)(xr + q * 8);
            raw[1] = *(const f32x4*)(xr + 32 + q * 8);
        } else {
            const float* xr = (row < split)
                ? ((const float*)xa_ + (size_t)row * DIM)
                : ((const float*)xb_ + (size_t)(row - split) * DIM);
            raw[0] = __builtin_nontemporal_load((const f32x4*)(xr + q * 8));
            raw[1] = __builtin_nontemporal_load((const f32x4*)(xr + q * 8 + 4));
            raw[2] = __builtin_nontemporal_load((const f32x4*)(xr + 32 + q * 8));
            raw[3] = __builtin_nontemporal_load((const f32x4*)(xr + 32 + q * 8 + 4));
        }
    };

    f32x4 cur[4];
    loadA(g0 * 16, cur);

#pragma unroll 1
    for (int gi = 0; gi < GPW; ++gi) {
        int g = g0 + gi;
        if (g >= ngroups) break;
        int r0 = g * 16;
        f32x4 nxt[4];
        bool pf = (gi + 1 < GPW) && (g + 1 < ngroups);
        if (pf) loadA(r0 + 16, nxt);

        bf16x8 A0, A1;
        if constexpr (BF16IN) {
            A0 = __builtin_bit_cast(bf16x8, cur[0]);
            A1 = __builtin_bit_cast(bf16x8, cur[1]);
        } else {
#pragma unroll
            for (int j = 0; j < 4; ++j) {
                A0[j] = (__bf16)cur[0][j]; A0[j + 4] = (__bf16)cur[1][j];
                A1[j] = (__bf16)cur[2][j]; A1[j + 4] = (__bf16)cur[3][j];
            }
        }

        f32x4 z = {0.f, 0.f, 0.f, 0.f};
        f32x4 acc[4];
#pragma unroll
        for (int nt = 0; nt < 4; ++nt)
            acc[nt] = mfma16(A1, Bf[nt][1], mfma16(A0, Bf[nt][0], z));

        f32x4 d4 = *(const f32x4*)(dinv + r0 + q * 4);
#pragma unroll
        for (int nt = 0; nt < 4; ++nt)
#pragma unroll
            for (int reg = 0; reg < 4; ++reg) {
                int row = r0 + q * 4 + reg;
                if (row < n)
                    h[(size_t)row * DIM + nt * 16 + t] =
                        (__bf16)(acc[nt][reg] * d4[reg]);
            }
#pragma unroll
        for (int i = 0; i < 4; ++i) cur[i] = nxt[i];
    }
}

// out[node] = b + dinv[node] * (h'[node] + sum_s h'[s]).  8 nodes/wave.
template <typename OutT>
__global__ __launch_bounds__(256) void agg_kernel(
    const int* __restrict__ rowptr, const int* __restrict__ srcs,
    const __bf16* __restrict__ h, const float* __restrict__ bias,
    const float* __restrict__ dinv, OutT* __restrict__ out, int n) {
    int lane = threadIdx.x & 63;
    int t8 = lane & 7;
    int wv = threadIdx.x >> 6;
    int node = (blockIdx.x * 4 + wv) * 8 + (lane >> 3);
    bool alive = node < n;
    int nd = alive ? node : (n - 1);
    int beg = rowptr[nd], end = rowptr[nd + 1];

    u16x8 sv = *(const u16x8*)(h + (size_t)nd * DIM + t8 * 8);
    float acc[8];
#pragma unroll
    for (int j = 0; j < 8; ++j) acc[j] = bf2f(sv[j]);

    int i = beg;
    while (i < end) {
        int idx = i + t8;
        int sl = (idx < end) ? srcs[idx] : 0;
        u16x8 vv[8];
#pragma unroll
        for (int k = 0; k < 8; ++k) {
            int s = __shfl(sl, (lane & 56) | k);
            vv[k] = *(const u16x8*)(h + (size_t)s * DIM + t8 * 8);
        }
#pragma unroll
        for (int k = 0; k < 8; ++k)
            if (i + k < end) {
#pragma unroll
                for (int j = 0; j < 8; ++j) acc[j] += bf2f(vv[k][j]);
            }
        i += 8;
    }

    float dn = dinv[nd];
    f32x4 b0 = *(const f32x4*)(bias + t8 * 8);
    f32x4 b1 = *(const f32x4*)(bias + t8 * 8 + 4);
    if (alive) {
        if constexpr (sizeof(OutT) == 4) {
            f32x4 o0, o1;
#pragma unroll
            for (int j = 0; j < 4; ++j) {
                o0[j] = fmaf(dn, acc[j],     b0[j]);
                o1[j] = fmaf(dn, acc[j + 4], b1[j]);
            }
            float* op = (float*)out + (size_t)node * DIM + t8 * 8;
            __builtin_nontemporal_store(o0, (f32x4*)op);
            __builtin_nontemporal_store(o1, (f32x4*)(op + 4));
        } else {
            bf16x8 o;
#pragma unroll
            for (int j = 0; j < 4; ++j) {
                o[j]     = (__bf16)fmaf(dn, acc[j],     b0[j]);
                o[j + 4] = (__bf16)fmaf(dn, acc[j + 4], b1[j]);
            }
            *(bf16x8*)((__bf16*)out + (size_t)node * DIM + t8 * 8) = o;
        }
    }
}

static inline size_t align16(size_t x) { return (x + 15) & ~(size_t)15; }

extern "C" void kernel_launch(void* const* d_in, const int* in_sizes, int n_in,
                              void* d_out, int out_size, void* d_ws, size_t ws_size,
                              hipStream_t stream) {
    const int* ei         = (const int*)d_in[0];
    const float* user_emb = (const float*)d_in[1];
    const float* item_emb = (const float*)d_in[2];
    const float* W1 = (const float*)d_in[3];
    const float* b1 = (const float*)d_in[4];
    const float* W2 = (const float*)d_in[5];
    const float* b2 = (const float*)d_in[6];
    float* out = (float*)d_out;

    const int E_ = in_sizes[0] / 2;
    const int NU = in_sizes[1] / DIM;
    const int NI = in_sizes[2] / DIM;
    const int N_ = NU + NI;
    const int NB = (N_ + BSPAN - 1) >> BSHIFT;   // 391

    // workspace layout (16B-aligned)
    char* p = (char*)d_ws;
    int* srcs   = (int*)p;               p += align16((size_t)E_ * 4);
    __bf16* h   = (__bf16*)p;            p += align16((size_t)N_ * DIM * 2);
    __bf16* t1  = (__bf16*)p;            p += align16((size_t)N_ * DIM * 2);
    float* dinv = (float*)p;             p += align16((size_t)N_ * 4);
    int* rowptr = (int*)p;               p += align16((size_t)(N_ + 1) * 4);
    int* bptr   = (int*)p;               p += align16((size_t)(MAXNB + 1) * 4);
    int* bcnt   = (int*)p;               p += align16((size_t)MAXNB * 4);   // |
    int* bcur0  = (int*)p;               p += align16((size_t)MAXNB * 4);   // | one memset
    int* bar    = (int*)p;               p += align16(16);                  // |
    // packed edge buffer aliases t1: fully consumed by bucket_sort before
    // agg1 writes t1.
    unsigned* packed = (unsigned*)t1;

    // zero bcnt|bcur0|bar in one memset node (replaces zero kernel)
    hipMemsetAsync(bcnt, 0, (size_t)MAXNB * 4 * 2 + 16, stream);

    // fused count+scan+scatter: cooperative launch (co-residency guarantee
    // for the hand-rolled atomic barrier; no cg::sync used)
    {
        int nblk = CSRB;
        void* args[] = {
            (void*)&ei, (void*)&packed, (void*)&bcnt, (void*)&bcur0,
            (void*)&bar, (void*)&bptr, (void*)&rowptr,
            (void*)&E_, (void*)&N_, (void*)&nblk,
        };
        hipLaunchCooperativeKernel((const void*)csr_count_scatter_kernel,
                                   dim3(CSRB), dim3(512), args, 0, stream);
    }
    bucket_sort_kernel<<<NB, 256, 0, stream>>>(packed, bptr, rowptr, srcs, dinv, N_);

    int NG = (N_ + 15) / 16;                       // 16-row groups
    int gblocks = (NG + 4 * GPW - 1) / (4 * GPW);  // 4 waves/block
    int ablocks = (N_ + 31) / 32;                  // 32 nodes/block (8/wave)

    // layer 1
    gemm_kernel<false><<<gblocks, 256, 0, stream>>>(user_emb, item_emb, NU,
                                                    W1, dinv, h, N_, NG);
    agg_kernel<__bf16><<<ablocks, 256, 0, stream>>>(rowptr, srcs, h, b1, dinv, t1, N_);
    // layer 2
    gemm_kernel<true><<<gblocks, 256, 0, stream>>>(t1, t1, N_,
                                                   W2, dinv, h, N_, NG);
    agg_kernel<float><<<ablocks, 256, 0, stream>>>(rowptr, srcs, h, b2, dinv, out, N_);
}

// Round 9
// 254.446 us; speedup vs baseline: 1.5630x; 1.2890x over previous
//
#include <hip/hip_runtime.h>

#define DIM 64
#define GPW 4    // 16-row groups per wave in gemm
#define BSHIFT 9
#define BSPAN 512      // nodes per bucket
#define MAXNB 512      // max buckets (N <= 262144; here N=200000 -> NB=391)
#define CNTB 256       // blocks in bucket_count / scatter

typedef __attribute__((ext_vector_type(8))) __bf16 bf16x8;
typedef __attribute__((ext_vector_type(8))) unsigned short u16x8;
typedef __attribute__((ext_vector_type(4))) float f32x4;

__device__ __forceinline__ f32x4 mfma16(bf16x8 a, bf16x8 b, f32x4 c) {
    return __builtin_amdgcn_mfma_f32_16x16x32_bf16(a, b, c, 0, 0, 0);
}

__device__ __forceinline__ float bf2f(unsigned short u) {
    return __uint_as_float((unsigned)u << 16);
}

// ---------- hierarchical CSR build (4 launches, no device sync) ----------

// P1: per-block bucket histogram -> bpart[bid][bucket]. Pure stores:
// no zero kernel, no global atomics.
__global__ __launch_bounds__(512) void bucket_count_kernel(
    const int* __restrict__ ei, int* __restrict__ bpart, int E_, int nblk) {
    __shared__ int hist[MAXNB];
    int tid = threadIdx.x;
    int bid = blockIdx.x;
    hist[tid] = 0;
    __syncthreads();
    int chunk = (E_ + nblk - 1) / nblk;
    int e0 = bid * chunk, e1 = min(E_, e0 + chunk);
    for (int e = e0 + tid; e < e1; e += 512)
        atomicAdd(&hist[ei[E_ + e] >> BSHIFT], 1);
    __syncthreads();
    bpart[bid * MAXNB + tid] = hist[tid];
}

// P2: 1 block reduces the 256x512 partials (coalesced columns) and
// exclusive-scans -> bptr, bcur.
__global__ __launch_bounds__(512) void bucket_scan_kernel(
    const int* __restrict__ bpart, int* __restrict__ bptr,
    int* __restrict__ bcur, int* __restrict__ rowptr,
    int nblk, int N_, int E_) {
    __shared__ int sm[512];
    int tid = threadIdx.x;
    int tot = 0;
#pragma unroll 8
    for (int blk = 0; blk < nblk; ++blk)
        tot += bpart[blk * MAXNB + tid];
    sm[tid] = tot;
    __syncthreads();
    for (int off = 1; off < 512; off <<= 1) {
        int t = 0;
        if (tid >= off) t = sm[tid - off];
        __syncthreads();
        if (tid >= off) sm[tid] += t;
        __syncthreads();
    }
    int ex = sm[tid] - tot;
    bptr[tid] = ex;
    bcur[tid] = ex;
    if (tid == 0) { bptr[MAXNB] = E_; rowptr[N_] = E_; }
}

// P3: coarse scatter into bucket-contiguous spans (R4-verified).
__global__ __launch_bounds__(512) void scatter_kernel(
    const int* __restrict__ ei, int* __restrict__ bcur,
    unsigned* __restrict__ packed, int E_, int nblk) {
    __shared__ int h[MAXNB];
    int tid = threadIdx.x;
    int chunk = (E_ + nblk - 1) / nblk;
    int e0 = blockIdx.x * chunk, e1 = min(E_, e0 + chunk);
    h[tid] = 0;
    __syncthreads();
    for (int e = e0 + tid; e < e1; e += 512)
        atomicAdd(&h[ei[E_ + e] >> BSHIFT], 1);
    __syncthreads();
    int c = h[tid];
    h[tid] = c ? atomicAdd(&bcur[tid], c) : 0;
    __syncthreads();
    for (int e = e0 + tid; e < e1; e += 512) {
        int s = ei[e], d = ei[E_ + e];
        int b = d >> BSHIFT;
        int pos = atomicAdd(&h[b], 1);
        packed[pos] = ((unsigned)s << BSHIFT) | (unsigned)(d & (BSPAN - 1));
    }
}

// P4: per-bucket fine sort (R4-verified). Emits rowptr + dinv.
__global__ __launch_bounds__(256) void bucket_sort_kernel(
    const unsigned* __restrict__ packed, const int* __restrict__ bptr,
    int* __restrict__ rowptr, int* __restrict__ srcs,
    float* __restrict__ dinv, int N_) {
    __shared__ int cnt[BSPAN];
    __shared__ int sc[256];
    int tid = threadIdx.x;
    int b = blockIdx.x;
    int beg = bptr[b], end = bptr[b + 1];
    int node0 = b << BSHIFT;
    int nn = min(BSPAN, N_ - node0);
    cnt[tid] = 0; cnt[tid + 256] = 0;
    __syncthreads();
    for (int i = beg + tid; i < end; i += 256)
        atomicAdd(&cnt[packed[i] & (BSPAN - 1)], 1);
    __syncthreads();
    int degA = cnt[tid], degB = cnt[tid + 256];
    int a0 = cnt[2 * tid], a1 = cnt[2 * tid + 1];
    if (tid < nn) dinv[node0 + tid] = rsqrtf((float)(1 + degA));
    if (tid + 256 < nn) dinv[node0 + tid + 256] = rsqrtf((float)(1 + degB));
    int tot = a0 + a1;
    sc[tid] = tot;
    __syncthreads();
    for (int off = 1; off < 256; off <<= 1) {
        int t = 0;
        if (tid >= off) t = sc[tid - off];
        __syncthreads();
        if (tid >= off) sc[tid] += t;
        __syncthreads();
    }
    int ex = sc[tid] - tot;
    cnt[2 * tid] = ex;
    cnt[2 * tid + 1] = ex + a0;
    __syncthreads();
    if (tid < nn) rowptr[node0 + tid] = beg + cnt[tid];
    if (tid + 256 < nn) rowptr[node0 + tid + 256] = beg + cnt[tid + 256];
    __syncthreads();
    for (int i = beg + tid; i < end; i += 256) {
        unsigned p = packed[i];
        int pos = atomicAdd(&cnt[p & (BSPAN - 1)], 1);
        srcs[beg + pos] = (int)(p >> BSHIFT);
    }
}

// ---------- layer kernels (R4-verified, plain loads/stores — no NT) ----------

// h'(bf16) = (x @ W) * dinv[row].   MFMA 16x16x32 bf16.
template <bool BF16IN>
__global__ __launch_bounds__(256) void gemm_kernel(
    const void* __restrict__ xa_, const void* __restrict__ xb_, int split,
    const float* __restrict__ W, const float* __restrict__ dinv,
    __bf16* __restrict__ h, int n, int ngroups) {
    int lane = threadIdx.x & 63;
    int q = lane >> 4, t = lane & 15;
    int wv = __builtin_amdgcn_readfirstlane(threadIdx.x >> 6);
    int g0 = (blockIdx.x * 4 + wv) * GPW;
    if (g0 >= ngroups) return;

    bf16x8 Bf[4][2];
#pragma unroll
    for (int nt = 0; nt < 4; ++nt)
#pragma unroll
        for (int kt = 0; kt < 2; ++kt) {
            bf16x8 f;
#pragma unroll
            for (int j = 0; j < 8; ++j)
                f[j] = (__bf16)W[(kt * 32 + q * 8 + j) * DIM + nt * 16 + t];
            Bf[nt][kt] = f;
        }

    auto loadA = [&](int r0, f32x4* raw) {
        int row = r0 + t;
        if (row >= n) row = n - 1;
        if constexpr (BF16IN) {
            const __bf16* xr = (const __bf16*)xa_ + (size_t)row * DIM;
            raw[0] = *(const f32x4*)(xr + q * 8);
            raw[1] = *(const f32x4*)(xr + 32 + q * 8);
        } else {
            const float* xr = (row < split)
                ? ((const float*)xa_ + (size_t)row * DIM)
                : ((const float*)xb_ + (size_t)(row - split) * DIM);
            raw[0] = *(const f32x4*)(xr + q * 8);
            raw[1] = *(const f32x4*)(xr + q * 8 + 4);
            raw[2] = *(const f32x4*)(xr + 32 + q * 8);
            raw[3] = *(const f32x4*)(xr + 32 + q * 8 + 4);
        }
    };

    f32x4 cur[4];
    loadA(g0 * 16, cur);

#pragma unroll 1
    for (int gi = 0; gi < GPW; ++gi) {
        int g = g0 + gi;
        if (g >= ngroups) break;
        int r0 = g * 16;
        f32x4 nxt[4];
        bool pf = (gi + 1 < GPW) && (g + 1 < ngroups);
        if (pf) loadA(r0 + 16, nxt);

        bf16x8 A0, A1;
        if constexpr (BF16IN) {
            A0 = __builtin_bit_cast(bf16x8, cur[0]);
            A1 = __builtin_bit_cast(bf16x8, cur[1]);
        } else {
#pragma unroll
            for (int j = 0; j < 4; ++j) {
                A0[j] = (__bf16)cur[0][j]; A0[j + 4] = (__bf16)cur[1][j];
                A1[j] = (__bf16)cur[2][j]; A1[j + 4] = (__bf16)cur[3][j];
            }
        }

        f32x4 z = {0.f, 0.f, 0.f, 0.f};
        f32x4 acc[4];
#pragma unroll
        for (int nt = 0; nt < 4; ++nt)
            acc[nt] = mfma16(A1, Bf[nt][1], mfma16(A0, Bf[nt][0], z));

        f32x4 d4 = *(const f32x4*)(dinv + r0 + q * 4);
#pragma unroll
        for (int nt = 0; nt < 4; ++nt)
#pragma unroll
            for (int reg = 0; reg < 4; ++reg) {
                int row = r0 + q * 4 + reg;
                if (row < n)
                    h[(size_t)row * DIM + nt * 16 + t] =
                        (__bf16)(acc[nt][reg] * d4[reg]);
            }
#pragma unroll
        for (int i = 0; i < 4; ++i) cur[i] = nxt[i];
    }
}

// out[node] = b + dinv[node] * (h'[node] + sum_s h'[s]).  8 nodes/wave
// (R4-verified): each 8-lane group owns one node's full 64-dim row.
template <typename OutT>
__global__ __launch_bounds__(256) void agg_kernel(
    const int* __restrict__ rowptr, const int* __restrict__ srcs,
    const __bf16* __restrict__ h, const float* __restrict__ bias,
    const float* __restrict__ dinv, OutT* __restrict__ out, int n) {
    int lane = threadIdx.x & 63;
    int t8 = lane & 7;
    int wv = threadIdx.x >> 6;
    int node = (blockIdx.x * 4 + wv) * 8 + (lane >> 3);
    bool alive = node < n;
    int nd = alive ? node : (n - 1);
    int beg = rowptr[nd], end = rowptr[nd + 1];

    u16x8 sv = *(const u16x8*)(h + (size_t)nd * DIM + t8 * 8);
    float acc[8];
#pragma unroll
    for (int j = 0; j < 8; ++j) acc[j] = bf2f(sv[j]);

    int i = beg;
    while (i < end) {
        int idx = i + t8;
        int sl = (idx < end) ? srcs[idx] : 0;
        u16x8 vv[8];
#pragma unroll
        for (int k = 0; k < 8; ++k) {
            int s = __shfl(sl, (lane & 56) | k);
            vv[k] = *(const u16x8*)(h + (size_t)s * DIM + t8 * 8);
        }
#pragma unroll
        for (int k = 0; k < 8; ++k)
            if (i + k < end) {
#pragma unroll
                for (int j = 0; j < 8; ++j) acc[j] += bf2f(vv[k][j]);
            }
        i += 8;
    }

    float dn = dinv[nd];
    f32x4 b0 = *(const f32x4*)(bias + t8 * 8);
    f32x4 b1 = *(const f32x4*)(bias + t8 * 8 + 4);
    if (alive) {
        if constexpr (sizeof(OutT) == 4) {
            f32x4 o0, o1;
#pragma unroll
            for (int j = 0; j < 4; ++j) {
                o0[j] = fmaf(dn, acc[j],     b0[j]);
                o1[j] = fmaf(dn, acc[j + 4], b1[j]);
            }
            float* op = (float*)out + (size_t)node * DIM + t8 * 8;
            *(f32x4*)op = o0;
            *(f32x4*)(op + 4) = o1;
        } else {
            bf16x8 o;
#pragma unroll
            for (int j = 0; j < 4; ++j) {
                o[j]     = (__bf16)fmaf(dn, acc[j],     b0[j]);
                o[j + 4] = (__bf16)fmaf(dn, acc[j + 4], b1[j]);
            }
            *(bf16x8*)((__bf16*)out + (size_t)node * DIM + t8 * 8) = o;
        }
    }
}

static inline size_t align16(size_t x) { return (x + 15) & ~(size_t)15; }

extern "C" void kernel_launch(void* const* d_in, const int* in_sizes, int n_in,
                              void* d_out, int out_size, void* d_ws, size_t ws_size,
                              hipStream_t stream) {
    const int* ei         = (const int*)d_in[0];
    const float* user_emb = (const float*)d_in[1];
    const float* item_emb = (const float*)d_in[2];
    const float* W1 = (const float*)d_in[3];
    const float* b1 = (const float*)d_in[4];
    const float* W2 = (const float*)d_in[5];
    const float* b2 = (const float*)d_in[6];
    float* out = (float*)d_out;

    const int E_ = in_sizes[0] / 2;
    const int NU = in_sizes[1] / DIM;
    const int NI = in_sizes[2] / DIM;
    const int N_ = NU + NI;
    const int NB = (N_ + BSPAN - 1) >> BSHIFT;   // 391

    // workspace layout (16B-aligned)
    char* p = (char*)d_ws;
    int* srcs   = (int*)p;               p += align16((size_t)E_ * 4);
    __bf16* h   = (__bf16*)p;            p += align16((size_t)N_ * DIM * 2);
    __bf16* t1  = (__bf16*)p;            p += align16((size_t)N_ * DIM * 2);
    float* dinv = (float*)p;             p += align16((size_t)N_ * 4);
    int* rowptr = (int*)p;               p += align16((size_t)(N_ + 1) * 4);
    int* bpart  = (int*)p;               p += align16((size_t)CNTB * MAXNB * 4);
    int* bptr   = (int*)p;               p += align16((size_t)(MAXNB + 1) * 4);
    int* bcur   = (int*)p;               p += align16((size_t)MAXNB * 4);
    // packed edge buffer aliases t1: fully consumed by bucket_sort before
    // agg1 writes t1.
    unsigned* packed = (unsigned*)t1;

    bucket_count_kernel<<<CNTB, 512, 0, stream>>>(ei, bpart, E_, CNTB);
    bucket_scan_kernel<<<1, 512, 0, stream>>>(bpart, bptr, bcur, rowptr,
                                              CNTB, N_, E_);
    scatter_kernel<<<CNTB, 512, 0, stream>>>(ei, bcur, packed, E_, CNTB);
    bucket_sort_kernel<<<NB, 256, 0, stream>>>(packed, bptr, rowptr, srcs, dinv, N_);

    int NG = (N_ + 15) / 16;                       // 16-row groups
    int gblocks = (NG + 4 * GPW - 1) / (4 * GPW);  // 4 waves/block
    int ablocks = (N_ + 31) / 32;                  // 32 nodes/block (8/wave)

    // layer 1
    gemm_kernel<false><<<gblocks, 256, 0, stream>>>(user_emb, item_emb, NU,
                                                    W1, dinv, h, N_, NG);
    agg_kernel<__bf16><<<ablocks, 256, 0, stream>>>(rowptr, srcs, h, b1, dinv, t1, N_);
    // layer 2
    gemm_kernel<true><<<gblocks, 256, 0, stream>>>(t1, t1, N_,
                                                   W2, dinv, h, N_, NG);
    agg_kernel<float><<<ablocks, 256, 0, stream>>>(rowptr, srcs, h, b2, dinv, out, N_);
}

// Round 10
// 247.118 us; speedup vs baseline: 1.6093x; 1.0297x over previous
//
#include <hip/hip_runtime.h>

#define DIM 64
#define GPW 4    // 16-row groups per wave in gemm
#define BSHIFT 9
#define BSPAN 512      // nodes per bucket
#define MAXNB 512      // max buckets (N <= 262144; here N=200000 -> NB=391)
#define CNTB 256       // CSR blocks in bucket_count / scatter

typedef __attribute__((ext_vector_type(8))) __bf16 bf16x8;
typedef __attribute__((ext_vector_type(8))) unsigned short u16x8;
typedef __attribute__((ext_vector_type(4))) float f32x4;

__device__ __forceinline__ f32x4 mfma16(bf16x8 a, bf16x8 b, f32x4 c) {
    return __builtin_amdgcn_mfma_f32_16x16x32_bf16(a, b, c, 0, 0, 0);
}

__device__ __forceinline__ float bf2f(unsigned short u) {
    return __uint_as_float((unsigned)u << 16);
}

// ---------- gemm bodies (device functions, callable packed or standalone) ----------

// h = x @ W  (UNSCALED when dinv==nullptr, else * dinv[row]).
// fp32 two-tensor input path.
__device__ __forceinline__ void gemm_f32_body(
    int bid, const float* __restrict__ xa_, const float* __restrict__ xb_,
    int split, const float* __restrict__ W, const float* __restrict__ dinv,
    __bf16* __restrict__ h, int n, int ngroups) {
    int lane = threadIdx.x & 63;
    int q = lane >> 4, t = lane & 15;
    int wv = __builtin_amdgcn_readfirstlane((threadIdx.x >> 6) & 3);
    int g0 = (bid * 4 + wv) * GPW;
    if (g0 >= ngroups) return;

    bf16x8 Bf[4][2];
#pragma unroll
    for (int nt = 0; nt < 4; ++nt)
#pragma unroll
        for (int kt = 0; kt < 2; ++kt) {
            bf16x8 f;
#pragma unroll
            for (int j = 0; j < 8; ++j)
                f[j] = (__bf16)W[(kt * 32 + q * 8 + j) * DIM + nt * 16 + t];
            Bf[nt][kt] = f;
        }

    auto loadA = [&](int r0, f32x4* raw) {
        int row = r0 + t;
        if (row >= n) row = n - 1;
        const float* xr = (row < split)
            ? (xa_ + (size_t)row * DIM)
            : (xb_ + (size_t)(row - split) * DIM);
        raw[0] = *(const f32x4*)(xr + q * 8);
        raw[1] = *(const f32x4*)(xr + q * 8 + 4);
        raw[2] = *(const f32x4*)(xr + 32 + q * 8);
        raw[3] = *(const f32x4*)(xr + 32 + q * 8 + 4);
    };

    f32x4 cur[4];
    loadA(g0 * 16, cur);

#pragma unroll 1
    for (int gi = 0; gi < GPW; ++gi) {
        int g = g0 + gi;
        if (g >= ngroups) break;
        int r0 = g * 16;
        f32x4 nxt[4];
        bool pf = (gi + 1 < GPW) && (g + 1 < ngroups);
        if (pf) loadA(r0 + 16, nxt);

        bf16x8 A0, A1;
#pragma unroll
        for (int j = 0; j < 4; ++j) {
            A0[j] = (__bf16)cur[0][j]; A0[j + 4] = (__bf16)cur[1][j];
            A1[j] = (__bf16)cur[2][j]; A1[j + 4] = (__bf16)cur[3][j];
        }

        f32x4 z = {0.f, 0.f, 0.f, 0.f};
        f32x4 acc[4];
#pragma unroll
        for (int nt = 0; nt < 4; ++nt)
            acc[nt] = mfma16(A1, Bf[nt][1], mfma16(A0, Bf[nt][0], z));

#pragma unroll
        for (int nt = 0; nt < 4; ++nt)
#pragma unroll
            for (int reg = 0; reg < 4; ++reg) {
                int row = r0 + q * 4 + reg;
                if (row < n)
                    h[(size_t)row * DIM + nt * 16 + t] = (__bf16)acc[nt][reg];
            }
#pragma unroll
        for (int i = 0; i < 4; ++i) cur[i] = nxt[i];
    }
}

// ---------- CSR build ----------

// P1 packed: blocks [0,CNTB) bucket-count; blocks [CNTB,...) gemm1 (x@W1,
// unscaled — independent of the CSR chain, overlaps it).
__global__ __launch_bounds__(256) void count_gemm_kernel(
    const int* __restrict__ ei, int* __restrict__ bpart, int E_,
    const float* __restrict__ ua, const float* __restrict__ ub, int split,
    const float* __restrict__ W1, __bf16* __restrict__ h, int n, int ngroups) {
    if (blockIdx.x >= CNTB) {
        gemm_f32_body(blockIdx.x - CNTB, ua, ub, split, W1, nullptr, h, n, ngroups);
        return;
    }
    __shared__ int hist[MAXNB];
    int tid = threadIdx.x;
    int bid = blockIdx.x;
    hist[tid] = 0; hist[tid + 256] = 0;
    __syncthreads();
    int chunk = (E_ + CNTB - 1) / CNTB;
    int e0 = bid * chunk, e1 = min(E_, e0 + chunk);
    for (int e = e0 + tid; e < e1; e += 256)
        atomicAdd(&hist[ei[E_ + e] >> BSHIFT], 1);
    __syncthreads();
    bpart[bid * MAXNB + tid] = hist[tid];
    bpart[bid * MAXNB + tid + 256] = hist[tid + 256];
}

// P2: 1 block reduces the CNTBx512 partials and exclusive-scans -> bptr, bcur.
__global__ __launch_bounds__(512) void bucket_scan_kernel(
    const int* __restrict__ bpart, int* __restrict__ bptr,
    int* __restrict__ bcur, int* __restrict__ rowptr,
    int nblk, int N_, int E_) {
    __shared__ int sm[512];
    int tid = threadIdx.x;
    int tot = 0;
#pragma unroll 8
    for (int blk = 0; blk < nblk; ++blk)
        tot += bpart[blk * MAXNB + tid];
    sm[tid] = tot;
    __syncthreads();
    for (int off = 1; off < 512; off <<= 1) {
        int t = 0;
        if (tid >= off) t = sm[tid - off];
        __syncthreads();
        if (tid >= off) sm[tid] += t;
        __syncthreads();
    }
    int ex = sm[tid] - tot;
    bptr[tid] = ex;
    bcur[tid] = ex;
    if (tid == 0) { bptr[MAXNB] = E_; rowptr[N_] = E_; }
}

// P3: coarse scatter into bucket-contiguous spans.
__global__ __launch_bounds__(512) void scatter_kernel(
    const int* __restrict__ ei, int* __restrict__ bcur,
    unsigned* __restrict__ packed, int E_, int nblk) {
    __shared__ int h[MAXNB];
    int tid = threadIdx.x;
    int chunk = (E_ + nblk - 1) / nblk;
    int e0 = blockIdx.x * chunk, e1 = min(E_, e0 + chunk);
    h[tid] = 0;
    __syncthreads();
    for (int e = e0 + tid; e < e1; e += 512)
        atomicAdd(&h[ei[E_ + e] >> BSHIFT], 1);
    __syncthreads();
    int c = h[tid];
    h[tid] = c ? atomicAdd(&bcur[tid], c) : 0;
    __syncthreads();
    for (int e = e0 + tid; e < e1; e += 512) {
        int s = ei[e], d = ei[E_ + e];
        int b = d >> BSHIFT;
        int pos = atomicAdd(&h[b], 1);
        packed[pos] = ((unsigned)s << BSHIFT) | (unsigned)(d & (BSPAN - 1));
    }
}

// P4: per-bucket fine sort. Emits rowptr + dinv.
__global__ __launch_bounds__(256) void bucket_sort_kernel(
    const unsigned* __restrict__ packed, const int* __restrict__ bptr,
    int* __restrict__ rowptr, int* __restrict__ srcs,
    float* __restrict__ dinv, int N_) {
    __shared__ int cnt[BSPAN];
    __shared__ int sc[256];
    int tid = threadIdx.x;
    int b = blockIdx.x;
    int beg = bptr[b], end = bptr[b + 1];
    int node0 = b << BSHIFT;
    int nn = min(BSPAN, N_ - node0);
    cnt[tid] = 0; cnt[tid + 256] = 0;
    __syncthreads();
    for (int i = beg + tid; i < end; i += 256)
        atomicAdd(&cnt[packed[i] & (BSPAN - 1)], 1);
    __syncthreads();
    int degA = cnt[tid], degB = cnt[tid + 256];
    int a0 = cnt[2 * tid], a1 = cnt[2 * tid + 1];
    if (tid < nn) dinv[node0 + tid] = rsqrtf((float)(1 + degA));
    if (tid + 256 < nn) dinv[node0 + tid + 256] = rsqrtf((float)(1 + degB));
    int tot = a0 + a1;
    sc[tid] = tot;
    __syncthreads();
    for (int off = 1; off < 256; off <<= 1) {
        int t = 0;
        if (tid >= off) t = sc[tid - off];
        __syncthreads();
        if (tid >= off) sc[tid] += t;
        __syncthreads();
    }
    int ex = sc[tid] - tot;
    cnt[2 * tid] = ex;
    cnt[2 * tid + 1] = ex + a0;
    __syncthreads();
    if (tid < nn) rowptr[node0 + tid] = beg + cnt[tid];
    if (tid + 256 < nn) rowptr[node0 + tid + 256] = beg + cnt[tid + 256];
    __syncthreads();
    for (int i = beg + tid; i < end; i += 256) {
        unsigned p = packed[i];
        int pos = atomicAdd(&cnt[p & (BSPAN - 1)], 1);
        srcs[beg + pos] = (int)(p >> BSHIFT);
    }
}

// ---------- layer kernels ----------

// Standalone gemm for layer 2: h2 = (t1 @ W2) * dinv[row], bf16 input.
__global__ __launch_bounds__(256) void gemm_bf16_kernel(
    const __bf16* __restrict__ x, const float* __restrict__ W,
    const float* __restrict__ dinv, __bf16* __restrict__ h, int n, int ngroups) {
    int lane = threadIdx.x & 63;
    int q = lane >> 4, t = lane & 15;
    int wv = __builtin_amdgcn_readfirstlane(threadIdx.x >> 6);
    int g0 = (blockIdx.x * 4 + wv) * GPW;
    if (g0 >= ngroups) return;

    bf16x8 Bf[4][2];
#pragma unroll
    for (int nt = 0; nt < 4; ++nt)
#pragma unroll
        for (int kt = 0; kt < 2; ++kt) {
            bf16x8 f;
#pragma unroll
            for (int j = 0; j < 8; ++j)
                f[j] = (__bf16)W[(kt * 32 + q * 8 + j) * DIM + nt * 16 + t];
            Bf[nt][kt] = f;
        }

    auto loadA = [&](int r0, f32x4* raw) {
        int row = r0 + t;
        if (row >= n) row = n - 1;
        const __bf16* xr = x + (size_t)row * DIM;
        raw[0] = *(const f32x4*)(xr + q * 8);
        raw[1] = *(const f32x4*)(xr + 32 + q * 8);
    };

    f32x4 cur[2];
    loadA(g0 * 16, cur);

#pragma unroll 1
    for (int gi = 0; gi < GPW; ++gi) {
        int g = g0 + gi;
        if (g >= ngroups) break;
        int r0 = g * 16;
        f32x4 nxt[2];
        bool pf = (gi + 1 < GPW) && (g + 1 < ngroups);
        if (pf) loadA(r0 + 16, nxt);

        bf16x8 A0 = __builtin_bit_cast(bf16x8, cur[0]);
        bf16x8 A1 = __builtin_bit_cast(bf16x8, cur[1]);

        f32x4 z = {0.f, 0.f, 0.f, 0.f};
        f32x4 acc[4];
#pragma unroll
        for (int nt = 0; nt < 4; ++nt)
            acc[nt] = mfma16(A1, Bf[nt][1], mfma16(A0, Bf[nt][0], z));

        f32x4 d4 = *(const f32x4*)(dinv + r0 + q * 4);
#pragma unroll
        for (int nt = 0; nt < 4; ++nt)
#pragma unroll
            for (int reg = 0; reg < 4; ++reg) {
                int row = r0 + q * 4 + reg;
                if (row < n)
                    h[(size_t)row * DIM + nt * 16 + t] =
                        (__bf16)(acc[nt][reg] * d4[reg]);
            }
        cur[0] = nxt[0]; cur[1] = nxt[1];
    }
}

// Aggregation, 8 nodes/wave (R4-verified structure).
// SRC_SCALE: gathered rows are UNSCALED (layer-1 path) -> multiply each
// gathered row by dinv[s] (and self by dinv[node]) during accumulation.
template <typename OutT, bool SRC_SCALE>
__global__ __launch_bounds__(256) void agg_kernel(
    const int* __restrict__ rowptr, const int* __restrict__ srcs,
    const __bf16* __restrict__ h, const float* __restrict__ bias,
    const float* __restrict__ dinv, OutT* __restrict__ out, int n) {
    int lane = threadIdx.x & 63;
    int t8 = lane & 7;
    int wv = threadIdx.x >> 6;
    int node = (blockIdx.x * 4 + wv) * 8 + (lane >> 3);
    bool alive = node < n;
    int nd = alive ? node : (n - 1);
    int beg = rowptr[nd], end = rowptr[nd + 1];
    float dn = dinv[nd];

    u16x8 sv = *(const u16x8*)(h + (size_t)nd * DIM + t8 * 8);
    float selfscale = SRC_SCALE ? dn : 1.f;
    float acc[8];
#pragma unroll
    for (int j = 0; j < 8; ++j) acc[j] = bf2f(sv[j]) * selfscale;

    int i = beg;
    while (i < end) {
        int idx = i + t8;
        int sl = (idx < end) ? srcs[idx] : 0;
        float dsl = 0.f;
        if (SRC_SCALE && idx < end) dsl = dinv[sl];
        u16x8 vv[8];
#pragma unroll
        for (int k = 0; k < 8; ++k) {
            int s = __shfl(sl, (lane & 56) | k);
            vv[k] = *(const u16x8*)(h + (size_t)s * DIM + t8 * 8);
        }
#pragma unroll
        for (int k = 0; k < 8; ++k)
            if (i + k < end) {
                float w = SRC_SCALE ? __shfl(dsl, (lane & 56) | k) : 1.f;
#pragma unroll
                for (int j = 0; j < 8; ++j)
                    acc[j] = SRC_SCALE ? fmaf(bf2f(vv[k][j]), w, acc[j])
                                       : (acc[j] + bf2f(vv[k][j]));
            }
        i += 8;
    }

    f32x4 b0 = *(const f32x4*)(bias + t8 * 8);
    f32x4 b1 = *(const f32x4*)(bias + t8 * 8 + 4);
    if (alive) {
        if constexpr (sizeof(OutT) == 4) {
            f32x4 o0, o1;
#pragma unroll
            for (int j = 0; j < 4; ++j) {
                o0[j] = fmaf(dn, acc[j],     b0[j]);
                o1[j] = fmaf(dn, acc[j + 4], b1[j]);
            }
            float* op = (float*)out + (size_t)node * DIM + t8 * 8;
            *(f32x4*)op = o0;
            *(f32x4*)(op + 4) = o1;
        } else {
            bf16x8 o;
#pragma unroll
            for (int j = 0; j < 4; ++j) {
                o[j]     = (__bf16)fmaf(dn, acc[j],     b0[j]);
                o[j + 4] = (__bf16)fmaf(dn, acc[j + 4], b1[j]);
            }
            *(bf16x8*)((__bf16*)out + (size_t)node * DIM + t8 * 8) = o;
        }
    }
}

static inline size_t align16(size_t x) { return (x + 15) & ~(size_t)15; }

extern "C" void kernel_launch(void* const* d_in, const int* in_sizes, int n_in,
                              void* d_out, int out_size, void* d_ws, size_t ws_size,
                              hipStream_t stream) {
    const int* ei         = (const int*)d_in[0];
    const float* user_emb = (const float*)d_in[1];
    const float* item_emb = (const float*)d_in[2];
    const float* W1 = (const float*)d_in[3];
    const float* b1 = (const float*)d_in[4];
    const float* W2 = (const float*)d_in[5];
    const float* b2 = (const float*)d_in[6];
    float* out = (float*)d_out;

    const int E_ = in_sizes[0] / 2;
    const int NU = in_sizes[1] / DIM;
    const int NI = in_sizes[2] / DIM;
    const int N_ = NU + NI;
    const int NB = (N_ + BSPAN - 1) >> BSHIFT;   // 391

    // workspace layout (16B-aligned)
    char* p = (char*)d_ws;
    int* srcs   = (int*)p;               p += align16((size_t)E_ * 4);
    __bf16* h   = (__bf16*)p;            p += align16((size_t)N_ * DIM * 2);
    __bf16* t1  = (__bf16*)p;            p += align16((size_t)N_ * DIM * 2);
    float* dinv = (float*)p;             p += align16((size_t)N_ * 4);
    int* rowptr = (int*)p;               p += align16((size_t)(N_ + 1) * 4);
    int* bpart  = (int*)p;               p += align16((size_t)CNTB * MAXNB * 4);
    int* bptr   = (int*)p;               p += align16((size_t)(MAXNB + 1) * 4);
    int* bcur   = (int*)p;               p += align16((size_t)MAXNB * 4);
    // packed edge buffer aliases t1: fully consumed by bucket_sort before
    // agg1 writes t1.
    unsigned* packed = (unsigned*)t1;

    int NG = (N_ + 15) / 16;                       // 16-row groups
    int gblocks = (NG + 4 * GPW - 1) / (4 * GPW);  // 4 waves/block
    int ablocks = (N_ + 31) / 32;                  // 32 nodes/block (8/wave)

    // P1: bucket-count packed with gemm1 (x@W1 unscaled — CSR-independent)
    count_gemm_kernel<<<CNTB + gblocks, 256, 0, stream>>>(
        ei, bpart, E_, user_emb, item_emb, NU, W1, h, N_, NG);
    bucket_scan_kernel<<<1, 512, 0, stream>>>(bpart, bptr, bcur, rowptr,
                                              CNTB, N_, E_);
    scatter_kernel<<<CNTB, 512, 0, stream>>>(ei, bcur, packed, E_, CNTB);
    bucket_sort_kernel<<<NB, 256, 0, stream>>>(packed, bptr, rowptr, srcs, dinv, N_);

    // layer 1 aggregate (applies dinv[s] per gathered row + dinv[node])
    agg_kernel<__bf16, true><<<ablocks, 256, 0, stream>>>(rowptr, srcs, h, b1,
                                                          dinv, t1, N_);
    // layer 2
    gemm_bf16_kernel<<<gblocks, 256, 0, stream>>>(t1, W2, dinv, h, N_, NG);
    agg_kernel<float, false><<<ablocks, 256, 0, stream>>>(rowptr, srcs, h, b2,
                                                          dinv, out, N_);
}